// Round 5
// baseline (118.205 us; speedup 1.0000x reference)
//
#include <hip/hip_runtime.h>

// Blockwise int8 dequant: out[i] = code[w[i] & 255] * absmax[i / 4096]
// w: [64Mi] int32 codes in [0,256); absmax: [16384] f32; code: [256] f32.
// Memory-bound stream: 256 MB read + 256 MB write.
// R4: 4 independent grid-stride-separated chains per iteration (64 B in
//     flight per thread) to deepen latency hiding; nt load/store kept.

typedef int   int4v   __attribute__((ext_vector_type(4)));
typedef float float4v __attribute__((ext_vector_type(4)));

__global__ __launch_bounds__(256) void dequant_blockwise_kernel(
    const int* __restrict__ w,
    const float* __restrict__ absmax,
    const float* __restrict__ code,
    float* __restrict__ out,
    long n4)  // number of vec4 elements (n / 4)
{
    __shared__ float lcode[256];
    lcode[threadIdx.x] = code[threadIdx.x];
    __syncthreads();

    const int4v* w4   = reinterpret_cast<const int4v*>(w);
    float4v*     out4 = reinterpret_cast<float4v*>(out);

    const long nthreads = (long)gridDim.x * blockDim.x;
    const long tid      = (long)blockIdx.x * blockDim.x + threadIdx.x;

    // Main loop: 4 perfectly-coalesced chains per iteration.
    long i = tid;
    for (; i + 3 * nthreads < n4; i += 4 * nthreads) {
        const long i0 = i;
        const long i1 = i + nthreads;
        const long i2 = i + 2 * nthreads;
        const long i3 = i + 3 * nthreads;

        int4v w0 = __builtin_nontemporal_load(w4 + i0);
        int4v w1 = __builtin_nontemporal_load(w4 + i1);
        int4v w2 = __builtin_nontemporal_load(w4 + i2);
        int4v w3 = __builtin_nontemporal_load(w4 + i3);

        float am0 = absmax[i0 >> 10];
        float am1 = absmax[i1 >> 10];
        float am2 = absmax[i2 >> 10];
        float am3 = absmax[i3 >> 10];

        float4v o0, o1, o2, o3;
        o0.x = lcode[w0.x & 255] * am0;
        o0.y = lcode[w0.y & 255] * am0;
        o0.z = lcode[w0.z & 255] * am0;
        o0.w = lcode[w0.w & 255] * am0;
        o1.x = lcode[w1.x & 255] * am1;
        o1.y = lcode[w1.y & 255] * am1;
        o1.z = lcode[w1.z & 255] * am1;
        o1.w = lcode[w1.w & 255] * am1;
        o2.x = lcode[w2.x & 255] * am2;
        o2.y = lcode[w2.y & 255] * am2;
        o2.z = lcode[w2.z & 255] * am2;
        o2.w = lcode[w2.w & 255] * am2;
        o3.x = lcode[w3.x & 255] * am3;
        o3.y = lcode[w3.y & 255] * am3;
        o3.z = lcode[w3.z & 255] * am3;
        o3.w = lcode[w3.w & 255] * am3;

        __builtin_nontemporal_store(o0, out4 + i0);
        __builtin_nontemporal_store(o1, out4 + i1);
        __builtin_nontemporal_store(o2, out4 + i2);
        __builtin_nontemporal_store(o3, out4 + i3);
    }
    // Tail (not taken for 64Mi elems with 2048x256 grid, kept for safety).
    for (; i < n4; i += nthreads) {
        int4v w0 = __builtin_nontemporal_load(w4 + i);
        float am0 = absmax[i >> 10];
        float4v o0;
        o0.x = lcode[w0.x & 255] * am0;
        o0.y = lcode[w0.y & 255] * am0;
        o0.z = lcode[w0.z & 255] * am0;
        o0.w = lcode[w0.w & 255] * am0;
        __builtin_nontemporal_store(o0, out4 + i);
    }
}

extern "C" void kernel_launch(void* const* d_in, const int* in_sizes, int n_in,
                              void* d_out, int out_size, void* d_ws, size_t ws_size,
                              hipStream_t stream) {
    const int*   w      = (const int*)d_in[0];
    const float* absmax = (const float*)d_in[1];
    const float* code   = (const float*)d_in[2];
    float*       out    = (float*)d_out;

    const long n  = (long)in_sizes[0];  // 8192*8192 = 67,108,864
    const long n4 = n >> 2;             // 16Mi vec4

    const int threads = 256;
    const int blocks  = 2048;           // 512Ki threads; 32 vec4/thread, 8 quad-iters
    dequant_blockwise_kernel<<<blocks, threads, 0, stream>>>(w, absmax, code, out, n4);
}

// Round 6
// 90.184 us; speedup vs baseline: 1.3107x; 1.3107x over previous
//
#include <hip/hip_runtime.h>

// Blockwise int8 dequant: out[i] = code[w[i] & 255] * absmax[i / 4096]
// w: [64Mi] int32 codes in [0,256); absmax: [16384] f32; code: [256] f32.
// Memory-bound stream: 256 MB read + 256 MB write.
// R5: A/B isolate vs R3 — nt LOADS kept (bypass L2 alloc for the 256MB read
//     stream), stores back to PLAIN (let L2 write-combine like the 6.9TB/s
//     fill kernel). 2 grid-stride-separated chains, each lane-coalesced.

typedef int   int4v   __attribute__((ext_vector_type(4)));
typedef float float4v __attribute__((ext_vector_type(4)));

__global__ __launch_bounds__(256) void dequant_blockwise_kernel(
    const int* __restrict__ w,
    const float* __restrict__ absmax,
    const float* __restrict__ code,
    float* __restrict__ out,
    long n4)  // number of vec4 elements (n / 4)
{
    __shared__ float lcode[256];
    lcode[threadIdx.x] = code[threadIdx.x];
    __syncthreads();

    const int4v* w4   = reinterpret_cast<const int4v*>(w);
    float4v*     out4 = reinterpret_cast<float4v*>(out);

    const long nthreads = (long)gridDim.x * blockDim.x;
    const long tid      = (long)blockIdx.x * blockDim.x + threadIdx.x;

    long i = tid;
    for (; i + nthreads < n4; i += 2 * nthreads) {
        const long i0 = i;
        const long i1 = i + nthreads;

        int4v w0 = __builtin_nontemporal_load(w4 + i0);
        int4v w1 = __builtin_nontemporal_load(w4 + i1);

        float am0 = absmax[i0 >> 10];
        float am1 = absmax[i1 >> 10];

        float4v o0, o1;
        o0.x = lcode[w0.x & 255] * am0;
        o0.y = lcode[w0.y & 255] * am0;
        o0.z = lcode[w0.z & 255] * am0;
        o0.w = lcode[w0.w & 255] * am0;
        o1.x = lcode[w1.x & 255] * am1;
        o1.y = lcode[w1.y & 255] * am1;
        o1.z = lcode[w1.z & 255] * am1;
        o1.w = lcode[w1.w & 255] * am1;

        out4[i0] = o0;   // plain store: L2 write-combine path
        out4[i1] = o1;
    }
    // Tail (not taken for 64Mi elems with 2048x256 grid, kept for safety).
    for (; i < n4; i += nthreads) {
        int4v w0 = __builtin_nontemporal_load(w4 + i);
        float am0 = absmax[i >> 10];
        float4v o0;
        o0.x = lcode[w0.x & 255] * am0;
        o0.y = lcode[w0.y & 255] * am0;
        o0.z = lcode[w0.z & 255] * am0;
        o0.w = lcode[w0.w & 255] * am0;
        out4[i] = o0;
    }
}

extern "C" void kernel_launch(void* const* d_in, const int* in_sizes, int n_in,
                              void* d_out, int out_size, void* d_ws, size_t ws_size,
                              hipStream_t stream) {
    const int*   w      = (const int*)d_in[0];
    const float* absmax = (const float*)d_in[1];
    const float* code   = (const float*)d_in[2];
    float*       out    = (float*)d_out;

    const long n  = (long)in_sizes[0];  // 8192*8192 = 67,108,864
    const long n4 = n >> 2;             // 16Mi vec4

    const int threads = 256;
    const int blocks  = 2048;           // 512Ki threads; 32 vec4/thread
    dequant_blockwise_kernel<<<blocks, threads, 0, stream>>>(w, absmax, code, out, n4);
}